// Round 2
// baseline (229.332 us; speedup 1.0000x reference)
//
#include <hip/hip_runtime.h>

#define NB 4
#define NH 16
#define NSEQ 2048
#define DH 64
#define SCALE 0.125f
#define QBLK 64
#define KVBLK 64

typedef _Float16 f16x8 __attribute__((ext_vector_type(8)));
typedef _Float16 f16x4 __attribute__((ext_vector_type(4)));
typedef float f32x4 __attribute__((ext_vector_type(4)));

#define KP 72   // Kt row pitch in f16 (144B: 16B-aligned rows, 2-way-only conflicts)
#define PP 72   // P row pitch in f16

__global__ __launch_bounds__(256)
void fa_fwd(const float* __restrict__ Qg, const float* __restrict__ Kg,
            const float* __restrict__ Vg, float* __restrict__ Og)
{
    __shared__ _Float16 Kt[KVBLK * KP];      // [kv][d] row-major, pitch 72
    __shared__ _Float16 Vt[KVBLK * DH];      // subtiled [kv/4][d/16][4][16] for tr_b16 reads
    __shared__ _Float16 Pt[4 * 16 * PP];     // per-wave [q][kv]

    const int tid  = threadIdx.x;
    const int lane = tid & 63;
    const int wv   = tid >> 6;
    const int l15  = lane & 15;
    const int g    = lane >> 4;

    const int bh    = blockIdx.y;
    const int qbase = blockIdx.x * QBLK;
    const size_t base = (size_t)bh * NSEQ * DH;

    // Q fragment (B-operand of swapped QK^T): lane holds Q[qrow][32*ks + 8*g + j] * SCALE
    const int qrow = qbase + wv * 16 + l15;
    f16x8 qf[2];
    {
        const float* qp = Qg + base + (size_t)qrow * DH;
#pragma unroll
        for (int ks = 0; ks < 2; ++ks)
#pragma unroll
            for (int j = 0; j < 8; ++j)
                qf[ks][j] = (_Float16)(qp[32 * ks + 8 * g + j] * SCALE);
    }

    f32x4 acc[4];   // acc[nt][r]: row q' = 4*g + r (wave-local), col d = 16*nt + l15
#pragma unroll
    for (int nt = 0; nt < 4; ++nt) acc[nt] = (f32x4){0.f, 0.f, 0.f, 0.f};
    float m_run = -INFINITY;
    float l_run = 0.f;

    _Float16* Pw = &Pt[wv * 16 * PP];
    const unsigned vtb = (unsigned)(size_t)(&Vt[0]) + (unsigned)(g * 1024 + l15 * 8);

    for (int t = 0; t < NSEQ / KVBLK; ++t) {
        const int kvb = t * KVBLK;
        __syncthreads();   // previous tile's LDS reads complete
#pragma unroll
        for (int i = 0; i < 4; ++i) {
            const int e  = i * 1024 + tid * 4;
            const int kv = e >> 6;        // 0..63
            const int d0 = e & 63;        // multiple of 4
            const float4 kf4 = *(const float4*)(Kg + base + (size_t)(kvb + kv) * DH + d0);
            const float4 vf4 = *(const float4*)(Vg + base + (size_t)(kvb + kv) * DH + d0);
            f16x4 kh, vh;
            kh[0] = (_Float16)kf4.x; kh[1] = (_Float16)kf4.y;
            kh[2] = (_Float16)kf4.z; kh[3] = (_Float16)kf4.w;
            vh[0] = (_Float16)vf4.x; vh[1] = (_Float16)vf4.y;
            vh[2] = (_Float16)vf4.z; vh[3] = (_Float16)vf4.w;
            *(f16x4*)&Kt[kv * KP + d0] = kh;
            // V subtile: block=(kv/4)*4 + d0/16, inner row kv&3, col d0&15
            *(f16x4*)&Vt[((kv >> 2) * 4 + (d0 >> 4)) * 64 + (kv & 3) * 16 + (d0 & 15)] = vh;
        }
        __syncthreads();

        // S^T = K · Q^T  (lane: q = l15; kv = 16*mt + 4*g + r)
        f32x4 s[4];
#pragma unroll
        for (int mt = 0; mt < 4; ++mt) {
            f32x4 a = (f32x4){0.f, 0.f, 0.f, 0.f};
#pragma unroll
            for (int ks = 0; ks < 2; ++ks) {
                f16x8 kf = *(const f16x8*)&Kt[(l15 + 16 * mt) * KP + 32 * ks + 8 * g];
                a = __builtin_amdgcn_mfma_f32_16x16x32_f16(kf, qf[ks], a, 0, 0, 0);
            }
            s[mt] = a;
        }

        // online softmax
        float tmax = -INFINITY;
#pragma unroll
        for (int mt = 0; mt < 4; ++mt)
#pragma unroll
            for (int r = 0; r < 4; ++r) tmax = fmaxf(tmax, s[mt][r]);
        tmax = fmaxf(tmax, __shfl_xor(tmax, 16));
        tmax = fmaxf(tmax, __shfl_xor(tmax, 32));
        const float m_new = fmaxf(m_run, tmax);

        float psum = 0.f;
        _Float16 ph[16];
#pragma unroll
        for (int mt = 0; mt < 4; ++mt)
#pragma unroll
            for (int r = 0; r < 4; ++r) {
                const float p = __expf(s[mt][r] - m_new);
                psum += p;
                ph[mt * 4 + r] = (_Float16)p;
            }
        psum += __shfl_xor(psum, 16);
        psum += __shfl_xor(psum, 32);
        const float fac = __expf(m_run - m_new);   // first tile: exp(-inf)=0
        l_run = l_run * fac + psum;
        m_run = m_new;

        // write P[q][kv] (4 contiguous kv per mt -> b64 writes)
#pragma unroll
        for (int mt = 0; mt < 4; ++mt) {
            f16x4 p4;
#pragma unroll
            for (int r = 0; r < 4; ++r) p4[r] = ph[mt * 4 + r];
            *(f16x4*)&Pw[l15 * PP + 16 * mt + 4 * g] = p4;
        }

        // rescale O by exp(m_old - m_new) for this lane's rows q' = 4*g + r
#pragma unroll
        for (int r = 0; r < 4; ++r) {
            const float fr = __shfl(fac, 4 * g + r);
#pragma unroll
            for (int nt = 0; nt < 4; ++nt) acc[nt][r] *= fr;
        }

        // PV: O += P · V
#pragma unroll
        for (int ks = 0; ks < 2; ++ks) {
            const f16x8 pa = *(const f16x8*)&Pw[l15 * PP + 32 * ks + 8 * g];
            f16x4 tr[8];   // [nt*2 + h]
#pragma unroll
            for (int nt = 0; nt < 4; ++nt)
#pragma unroll
                for (int h = 0; h < 2; ++h) {
                    const unsigned a = vtb + (unsigned)(ks * 4096 + h * 512 + nt * 128);
                    asm volatile("ds_read_b64_tr_b16 %0, %1"
                                 : "=v"(tr[nt * 2 + h]) : "v"(a));
                }
            asm volatile("s_waitcnt lgkmcnt(0)" ::: "memory");
            __builtin_amdgcn_sched_barrier(0);
#pragma unroll
            for (int nt = 0; nt < 4; ++nt) {
                f16x8 vb;
#pragma unroll
                for (int j = 0; j < 4; ++j) {
                    vb[j]     = tr[nt * 2][j];
                    vb[4 + j] = tr[nt * 2 + 1][j];
                }
                acc[nt] = __builtin_amdgcn_mfma_f32_16x16x32_f16(pa, vb, acc[nt], 0, 0, 0);
            }
        }
    }

    // epilogue: O / l, store fp32
#pragma unroll
    for (int r = 0; r < 4; ++r) {
        const float lr  = __shfl(l_run, 4 * g + r);
        const float inv = 1.0f / lr;
        const int row = qbase + wv * 16 + 4 * g + r;
        float* op = Og + base + (size_t)row * DH;
#pragma unroll
        for (int nt = 0; nt < 4; ++nt)
            op[16 * nt + l15] = acc[nt][r] * inv;
    }
}

extern "C" void kernel_launch(void* const* d_in, const int* in_sizes, int n_in,
                              void* d_out, int out_size, void* d_ws, size_t ws_size,
                              hipStream_t stream) {
    const float* Q = (const float*)d_in[0];
    const float* K = (const float*)d_in[1];
    const float* V = (const float*)d_in[2];
    float* O = (float*)d_out;
    dim3 grid(NSEQ / QBLK, NB * NH);
    fa_fwd<<<grid, dim3(256, 1, 1), 0, stream>>>(Q, K, V, O);
}

// Round 3
// 134.079 us; speedup vs baseline: 1.7104x; 1.7104x over previous
//
#include <hip/hip_runtime.h>

#define NSEQ 2048
#define DH 64
#define SCALE 0.125f
#define QBLK 256
#define KVBLK 64
#define NTILE (NSEQ / KVBLK)
#define KP 72   // Kt row pitch (144B, 16B-aligned, conflict-free b128 reads)
#define PP 72   // P row pitch

typedef _Float16 f16x8 __attribute__((ext_vector_type(8)));
typedef _Float16 f16x4 __attribute__((ext_vector_type(4)));
typedef float f32x4 __attribute__((ext_vector_type(4)));

__global__ __launch_bounds__(512)
void fa_fwd(const float* __restrict__ Qg, const float* __restrict__ Kg,
            const float* __restrict__ Vg, float* __restrict__ Og)
{
    __shared__ _Float16 Kt[2][KVBLK * KP];   // 18432 B, double-buffered
    __shared__ _Float16 Vt[2][KVBLK * DH];   // 16384 B, subtiled for tr_b16
    __shared__ _Float16 Pt[8][16 * PP];      // 18432 B, per-wave

    const int tid  = threadIdx.x;
    const int lane = tid & 63;
    const int wv   = tid >> 6;      // 0..7
    const int l15  = lane & 15;
    const int g    = lane >> 4;

    // XCD-aware swizzle: 512 blocks, 8 XCDs -> 64 contiguous work items per XCD
    const int id  = blockIdx.x;
    const int w   = (id & 7) * 64 + (id >> 3);
    const int bh  = w >> 3;               // 0..63
    const int qb0 = (w & 7) * QBLK;       // 0..1792
    const size_t base = (size_t)bh * NSEQ * DH;

    // Q fragments: qf[u][ks], lane holds Q[qb0+wv*32+u*16+l15][32ks+8g+j]*SCALE
    f16x8 qf[2][2];
#pragma unroll
    for (int u = 0; u < 2; ++u) {
        const float* qp = Qg + base + (size_t)(qb0 + wv * 32 + u * 16 + l15) * DH;
#pragma unroll
        for (int ks = 0; ks < 2; ++ks)
#pragma unroll
            for (int j = 0; j < 8; ++j)
                qf[u][ks][j] = (_Float16)(qp[32 * ks + 8 * g + j] * SCALE);
    }

    f32x4 acc[2][4];   // acc[u][nt][r]: row = 4g+r (sub-tile u), col = 16nt+l15
#pragma unroll
    for (int u = 0; u < 2; ++u)
#pragma unroll
        for (int nt = 0; nt < 4; ++nt)
            acc[u][nt] = (f32x4){0.f, 0.f, 0.f, 0.f};
    float m_run[2] = {-INFINITY, -INFINITY};
    float l_run[2] = {0.f, 0.f};

    // staging map: 4096 elems / 512 thr = 8 each (2 float4) per K and V
    const int ea  = tid * 4;
    const int eb  = 2048 + tid * 4;
    const int kva = ea >> 6, d0a = ea & 63;
    const int kvb = eb >> 6, d0b = eb & 63;
    const float* Kbp = Kg + base;
    const float* Vbp = Vg + base;
    const int vta = ((kva >> 2) * 4 + (d0a >> 4)) * 64 + (kva & 3) * 16 + (d0a & 15);
    const int vtb = ((kvb >> 2) * 4 + (d0b >> 4)) * 64 + (kvb & 3) * 16 + (d0b & 15);

    float4 kra, krb, vra, vrb;
    kra = *(const float4*)(Kbp + kva * DH + d0a);
    krb = *(const float4*)(Kbp + kvb * DH + d0b);
    vra = *(const float4*)(Vbp + kva * DH + d0a);
    vrb = *(const float4*)(Vbp + kvb * DH + d0b);

#define STAGE_WRITE(bb) do { \
        f16x4 h; \
        h[0] = (_Float16)kra.x; h[1] = (_Float16)kra.y; h[2] = (_Float16)kra.z; h[3] = (_Float16)kra.w; \
        *(f16x4*)&Kt[bb][kva * KP + d0a] = h; \
        h[0] = (_Float16)krb.x; h[1] = (_Float16)krb.y; h[2] = (_Float16)krb.z; h[3] = (_Float16)krb.w; \
        *(f16x4*)&Kt[bb][kvb * KP + d0b] = h; \
        h[0] = (_Float16)vra.x; h[1] = (_Float16)vra.y; h[2] = (_Float16)vra.z; h[3] = (_Float16)vra.w; \
        *(f16x4*)&Vt[bb][vta] = h; \
        h[0] = (_Float16)vrb.x; h[1] = (_Float16)vrb.y; h[2] = (_Float16)vrb.z; h[3] = (_Float16)vrb.w; \
        *(f16x4*)&Vt[bb][vtb] = h; \
    } while (0)

    STAGE_WRITE(0);
    __syncthreads();

    _Float16* Pw = &Pt[wv][0];
    const unsigned vtrb = (unsigned)(size_t)(&Vt[0][0]) + (unsigned)(g * 1024 + l15 * 8);

    for (int t = 0; t < NTILE; ++t) {
        const int c = t & 1;

        // prefetch tile t+1 into registers (latency hidden under compute)
        if (t + 1 < NTILE) {
            const float* kp = Kbp + (size_t)(t + 1) * KVBLK * DH;
            const float* vp = Vbp + (size_t)(t + 1) * KVBLK * DH;
            kra = *(const float4*)(kp + kva * DH + d0a);
            krb = *(const float4*)(kp + kvb * DH + d0b);
            vra = *(const float4*)(vp + kva * DH + d0a);
            vrb = *(const float4*)(vp + kvb * DH + d0b);
        }

        // K fragments, shared by both q-sub-tiles
        f16x8 kf[4][2];
#pragma unroll
        for (int mt = 0; mt < 4; ++mt)
#pragma unroll
            for (int ks = 0; ks < 2; ++ks)
                kf[mt][ks] = *(const f16x8*)&Kt[c][(l15 + 16 * mt) * KP + 32 * ks + 8 * g];

        const unsigned vb0 = vtrb + (unsigned)(c * 8192);

#pragma unroll
        for (int u = 0; u < 2; ++u) {
            // S^T = K · Q^T  (lane: q = l15; kv = 16mt + 4g + r)
            f32x4 s[4];
#pragma unroll
            for (int mt = 0; mt < 4; ++mt) {
                s[mt] = (f32x4){0.f, 0.f, 0.f, 0.f};
#pragma unroll
                for (int ks = 0; ks < 2; ++ks)
                    s[mt] = __builtin_amdgcn_mfma_f32_16x16x32_f16(kf[mt][ks], qf[u][ks], s[mt], 0, 0, 0);
            }

            float tmax = -INFINITY;
#pragma unroll
            for (int mt = 0; mt < 4; ++mt)
#pragma unroll
                for (int r = 0; r < 4; ++r) tmax = fmaxf(tmax, s[mt][r]);
            tmax = fmaxf(tmax, __shfl_xor(tmax, 16));
            tmax = fmaxf(tmax, __shfl_xor(tmax, 32));

            // T13 defer-max: rescale only when the tile max outgrows m_run+8
            if (!__all(tmax <= m_run[u] + 8.f)) {
                const float m_new = fmaxf(m_run[u], tmax);
                const float fac = __expf(m_run[u] - m_new);   // first tile: 0
                l_run[u] *= fac;
                m_run[u] = m_new;
#pragma unroll
                for (int r = 0; r < 4; ++r) {
                    const float fr = __shfl(fac, 4 * g + r);
#pragma unroll
                    for (int nt = 0; nt < 4; ++nt) acc[u][nt][r] *= fr;
                }
            }

            // P = exp(s - m_run), bounded by e^8; write per-wave P tile
            float psum = 0.f;
#pragma unroll
            for (int mt = 0; mt < 4; ++mt) {
                f16x4 p4;
#pragma unroll
                for (int r = 0; r < 4; ++r) {
                    const float p = __expf(s[mt][r] - m_run[u]);
                    psum += p;
                    p4[r] = (_Float16)p;
                }
                *(f16x4*)&Pw[l15 * PP + 16 * mt + 4 * g] = p4;
            }
            psum += __shfl_xor(psum, 16);
            psum += __shfl_xor(psum, 32);
            l_run[u] += psum;

            // PV: acc[u] += P · V
#pragma unroll
            for (int ks = 0; ks < 2; ++ks) {
                const f16x8 pa = *(const f16x8*)&Pw[l15 * PP + 32 * ks + 8 * g];
                f16x4 tr[8];
#pragma unroll
                for (int nt = 0; nt < 4; ++nt)
#pragma unroll
                    for (int h2 = 0; h2 < 2; ++h2) {
                        const unsigned a = vb0 + (unsigned)(ks * 4096 + h2 * 512 + nt * 128);
                        asm volatile("ds_read_b64_tr_b16 %0, %1"
                                     : "=v"(tr[nt * 2 + h2]) : "v"(a));
                    }
                asm volatile("s_waitcnt lgkmcnt(0)" ::: "memory");
                __builtin_amdgcn_sched_barrier(0);
#pragma unroll
                for (int nt = 0; nt < 4; ++nt) {
                    f16x8 vbf;
#pragma unroll
                    for (int j = 0; j < 4; ++j) {
                        vbf[j]     = tr[nt * 2][j];
                        vbf[4 + j] = tr[nt * 2 + 1][j];
                    }
                    acc[u][nt] = __builtin_amdgcn_mfma_f32_16x16x32_f16(pa, vbf, acc[u][nt], 0, 0, 0);
                }
            }
        }

        // write next tile into the other buffer; single barrier per tile
        if (t + 1 < NTILE) {
            STAGE_WRITE(c ^ 1);
            __syncthreads();
        }
    }

    // epilogue: O = acc / l
#pragma unroll
    for (int u = 0; u < 2; ++u)
#pragma unroll
        for (int r = 0; r < 4; ++r) {
            const float lr  = __shfl(l_run[u], 4 * g + r);
            const float inv = 1.0f / lr;
            const int row = qb0 + wv * 32 + u * 16 + 4 * g + r;
            float* op = Og + base + (size_t)row * DH;
#pragma unroll
            for (int nt = 0; nt < 4; ++nt)
                op[16 * nt + l15] = acc[u][nt][r] * inv;
        }
}

extern "C" void kernel_launch(void* const* d_in, const int* in_sizes, int n_in,
                              void* d_out, int out_size, void* d_ws, size_t ws_size,
                              hipStream_t stream) {
    const float* Q = (const float*)d_in[0];
    const float* K = (const float*)d_in[1];
    const float* V = (const float*)d_in[2];
    float* O = (float*)d_out;
    fa_fwd<<<dim3(512, 1, 1), dim3(512, 1, 1), 0, stream>>>(Q, K, V, O);
}